// Round 3
// baseline (512.539 us; speedup 1.0000x reference)
//
#include <hip/hip_runtime.h>

typedef __attribute__((ext_vector_type(8))) short short8;
typedef __attribute__((ext_vector_type(4))) float floatx4;
typedef __attribute__((ext_vector_type(16))) float f32x16;
typedef unsigned int u32;
typedef unsigned short u16;

// ---------- helpers ----------
__device__ __forceinline__ u16 f2bf(float f) {
  u32 u = __float_as_uint(f);
  u += 0x7FFFu + ((u >> 16) & 1u);   // RNE
  return (u16)(u >> 16);
}

typedef const __attribute__((address_space(1))) u32* gp1_t;
typedef __attribute__((address_space(3))) u32* lp3_t;

__device__ __forceinline__ void gld16(const void* g, void* l) {
  // async global -> LDS, 16B per lane; LDS dest is wave-uniform base + lane*16
  __builtin_amdgcn_global_load_lds((gp1_t)g, (lp3_t)l, 16, 0, 0);
}

// ---------- kernel 1: x fp32 -> bf16 ----------
__global__ __launch_bounds__(256) void xconv(const float* __restrict__ x,
                                             u16* __restrict__ xb, long long n4) {
  long long i = (long long)blockIdx.x * 256 + threadIdx.x;
  if (i >= n4) return;
  float4 v = ((const float4*)x)[i];
  ushort4 o;
  o.x = f2bf(v.x); o.y = f2bf(v.y); o.z = f2bf(v.z); o.w = f2bf(v.w);
  ((ushort4*)xb)[i] = o;
}

// ---------- kernel 2: dequant int4 -> Wt[n][k] bf16 (transposed) ----------
__global__ __launch_bounds__(256) void dequant(
    const int* __restrict__ qw, const int* __restrict__ qz,
    const int* __restrict__ qs, const float* __restrict__ qsz,
    const float* __restrict__ qss, const int* __restrict__ gidx,
    u16* __restrict__ Wt, int IN, int OUT) {
  const int n = blockIdx.x * 64 + (threadIdx.x & 63);
  const int w = threadIdx.x >> 6;            // 0..3
  const int k0 = blockIdx.y * 128 + w * 32;  // one 32-wide group per wave-slice
  const int g = gidx[k0];                    // uniform across wave
  const int kk0 = k0 >> 3;                   // 4 packed rows
  const int zq = ((qz[(size_t)g * (OUT >> 3) + (n >> 3)] >> (4 * (n & 7))) & 15) + 1;
  const float sc = ((float)qs[(size_t)g * OUT + n] - qsz[g]) * qss[g];
  u16* dst = Wt + (size_t)n * IN + k0;
#pragma unroll
  for (int j = 0; j < 4; ++j) {
    const int w32 = qw[(size_t)(kk0 + j) * OUT + n];   // coalesced across lanes
    u16 o[8];
#pragma unroll
    for (int s = 0; s < 8; ++s)
      o[s] = f2bf((float)(((w32 >> (4 * s)) & 15) - zq) * sc);
    uint4 pk;
    pk.x = (u32)o[0] | ((u32)o[1] << 16);
    pk.y = (u32)o[2] | ((u32)o[3] << 16);
    pk.z = (u32)o[4] | ((u32)o[5] << 16);
    pk.w = (u32)o[6] | ((u32)o[7] << 16);
    *(uint4*)(dst + j * 8) = pk;
  }
}

// ---------- kernel 3: 256x256 4-phase 32x32-MFMA bf16 GEMM ----------
// C = A(MxK)*Bt(NxK)^T.  8 waves (2m x 4n), per-wave 128x64 C as 4x2 tiles
// of 32x32 (mfma_f32_32x32x16_bf16: higher pipe ceiling than 16x16, half
// the instruction count).  BK=64, buf0 = even K-tiles, buf1 = odd.
// Iter = 2 K-tiles = 4 phases of 16 MFMA; per phase: A-frags for 2 mt
// (8 ds_read_b128) [+ B-frags 8 reads on first phase of each tile], stage
// one full operand tile (4 x gld16), barrier, 16 MFMA (setprio), barrier.
// Counted vmcnt(4) only at ph1/ph3 ends (never 0 in steady state).
// Stage rotation (iter i computes tiles 2i/buf0, 2i+1/buf1):
//   ph0: buf1.A<-t2i+1 (read ph2)      ph1: buf0.B<-t2i+2 (read next ph0)
//   ph2: buf0.A<-t2i+2 (read next ph0) ph3: buf1.B<-t2i+3 (read next ph2)
//   ph1-end vmcnt(4): drains buf1.B(prev ph3) + buf1.A(ph0) before ph2.
//   ph3-end vmcnt(4): drains buf0.B(ph1) + buf0.A(ph2) before next ph0.
// Swizzle: row stride 64 bf16 = 128B = 8 granules; store granule c at
// c^(row&7) (pre-swizzled global source col; gld_lds writes linearly),
// undo on ds_read.  Read granule = (ks*2 + (lane>>5)) ^ (lane&7): each
// consecutive-8-lane group spans all 8 granules -> conflict-free.
// Layouts: A row=lane&31, k=(lane>>5)*8+j; B col=lane&31, same k;
// C/D col=lane&31, row=(reg&3)+8*(reg>>2)+4*(lane>>5)  [m74/m101].
#define VM4 asm volatile("s_waitcnt vmcnt(4)" ::: "memory")
#define VM0 asm volatile("s_waitcnt vmcnt(0)" ::: "memory")

__global__ __launch_bounds__(512, 2) void gemm256(const u16* __restrict__ A,
                                                  const u16* __restrict__ Bt,
                                                  float* __restrict__ C,
                                                  int M, int N, int K) {
  __shared__ u16 As[2][16384];
  __shared__ u16 Bs[2][16384];
  const int tid = threadIdx.x;
  const int lane = tid & 63;
  const int wave = tid >> 6;          // 0..7
  const int wm = wave >> 2;           // 0..1
  const int wn = wave & 3;            // 0..3
  const int l31 = lane & 31, hi = lane >> 5, l7 = lane & 7;

  // bijective XCD-aware block swizzle (m204 form)
  const int nbx = N >> 8;
  const int nwg = gridDim.x;
  const int bid = blockIdx.x;
  const int q8 = nwg >> 3, r8 = nwg & 7;
  const int xcd = bid & 7, loc = bid >> 3;
  const int swz = (xcd < r8 ? xcd * (q8 + 1) : r8 * (q8 + 1) + (xcd - r8) * q8) + loc;
  const int n0 = (swz % nbx) << 8;
  const int m0 = (swz / nbx) << 8;

  f32x16 acc[4][2] = {};

  // ---- staging source (per-thread; carries the store swizzle) ----
  const int srow = lane >> 3;
  const int sch8 = ((lane & 7) ^ (srow & 7)) * 8;
  const u16* aS = A + (size_t)(m0 + wave * 8 + srow) * K + sch8;
  const u16* bS = Bt + (size_t)(n0 + wave * 8 + srow) * K + sch8;

#define STAGE_A(buf, h, kt) do {                                              \
    const u16* s_ = aS + (size_t)(h) * 128 * K + (size_t)(kt) * 64;           \
    u16* d_ = &As[buf][((h) * 128 + wave * 8) * 64];                          \
    gld16(s_, d_); gld16(s_ + (size_t)64 * K, d_ + 4096);                     \
  } while (0)
#define STAGE_B(buf, h, kt) do {                                              \
    const u16* s_ = bS + (size_t)(h) * 128 * K + (size_t)(kt) * 64;           \
    u16* d_ = &Bs[buf][((h) * 128 + wave * 8) * 64];                          \
    gld16(s_, d_); gld16(s_ + (size_t)64 * K, d_ + 4096);                     \
  } while (0)

  // ---- fragment read bases (swizzle undone on granule) ----
  int ko[4];
#pragma unroll
  for (int ks = 0; ks < 4; ++ks) ko[ks] = ((ks * 2 + hi) ^ l7) * 8;
  const u16* a0rd = &As[0][(wm * 128 + l31) * 64];
  const u16* a1rd = &As[1][(wm * 128 + l31) * 64];
  const u16* b0rd = &Bs[0][(wn * 64 + l31) * 64];
  const u16* b1rd = &Bs[1][(wn * 64 + l31) * 64];

  short8 aF[2][4], bF[2][4];

#define PHASE(ARD, BRD, q, LOADB, STG, VMW) do {                              \
    if (LOADB) {                                                              \
      _Pragma("unroll") for (int nt = 0; nt < 2; ++nt)                        \
        _Pragma("unroll") for (int ks = 0; ks < 4; ++ks)                      \
          bF[nt][ks] = *(const short8*)((BRD) + nt * 2048 + ko[ks]);          \
    }                                                                         \
    _Pragma("unroll") for (int j = 0; j < 2; ++j)                             \
      _Pragma("unroll") for (int ks = 0; ks < 4; ++ks)                        \
        aF[j][ks] = *(const short8*)((ARD) + (2 * (q) + j) * 2048 + ko[ks]);  \
    STG;                                                                      \
    __builtin_amdgcn_s_barrier();                                             \
    __builtin_amdgcn_s_setprio(1);                                            \
    _Pragma("unroll") for (int ks = 0; ks < 4; ++ks)                          \
      _Pragma("unroll") for (int j = 0; j < 2; ++j)                           \
        _Pragma("unroll") for (int nt = 0; nt < 2; ++nt)                      \
          acc[2 * (q) + j][nt] = __builtin_amdgcn_mfma_f32_32x32x16_bf16(     \
              aF[j][ks], bF[nt][ks], acc[2 * (q) + j][nt], 0, 0, 0);          \
    __builtin_amdgcn_s_setprio(0);                                            \
    VMW;                                                                      \
    __builtin_amdgcn_s_barrier();                                             \
  } while (0)

  // ---- prologue: buf0 <- tile0 (B,A), buf1.B <- tile1; wait buf0 only ----
  STAGE_B(0, 0, 0); STAGE_B(0, 1, 0);
  STAGE_A(0, 0, 0); STAGE_A(0, 1, 0);
  STAGE_B(1, 0, 1); STAGE_B(1, 1, 1);
  VM4;                                    // oldest 8 = buf0 complete
  __builtin_amdgcn_s_barrier();

  const int NI = K >> 7;                  // iters of 2 K-tiles
  for (int i = 0; i < NI; ++i) {
    const int kt = 2 * i;
    const bool full = (i < NI - 1);
    PHASE(a0rd, b0rd, 0, 1, { STAGE_A(1, 0, kt + 1); STAGE_A(1, 1, kt + 1); },
          (void)0);
    PHASE(a0rd, b0rd, 1, 0,
          { if (full) { STAGE_B(0, 0, kt + 2); STAGE_B(0, 1, kt + 2); } },
          { if (full) { VM4; } else { VM0; } });
    PHASE(a1rd, b1rd, 0, 1,
          { if (full) { STAGE_A(0, 0, kt + 2); STAGE_A(0, 1, kt + 2); } },
          (void)0);
    PHASE(a1rd, b1rd, 1, 0,
          { if (full) { STAGE_B(1, 0, kt + 3); STAGE_B(1, 1, kt + 3); } },
          { if (full) { VM4; } });
  }
#undef PHASE
#undef STAGE_A
#undef STAGE_B

  // ---- epilogue: C/D col=lane&31, row=(r&3)+8*(r>>2)+4*hi ----
#pragma unroll
  for (int mt = 0; mt < 4; ++mt)
#pragma unroll
    for (int nt = 0; nt < 2; ++nt)
#pragma unroll
      for (int r = 0; r < 16; ++r) {
        int row = m0 + wm * 128 + mt * 32 + (r & 3) + 8 * (r >> 2) + 4 * hi;
        int col = n0 + wn * 64 + nt * 32 + l31;
        C[(size_t)row * N + col] = acc[mt][nt][r];
      }
}

// ---------- kernel 3b (fallback): 128x128 bf16 GEMM ----------
__global__ __launch_bounds__(256) void gemm(const u16* __restrict__ A,
                                            const u16* __restrict__ Bt,
                                            float* __restrict__ C,
                                            int M, int N, int K) {
  __shared__ u16 As[128 * 64];
  __shared__ u16 Bs[128 * 64];
  const int tid = threadIdx.x;
  const int lane = tid & 63;
  const int wave = tid >> 6;
  const int wm = wave & 1, wn = wave >> 1;
  const int lr = lane & 15, quad = lane >> 4;
  const int m0 = blockIdx.y * 128, n0 = blockIdx.x * 128;

  floatx4 acc[4][4] = {};

  const int srowB = (lane >> 3);
  const int schunk = (lane & 7) ^ srowB;
  const int rowA0 = wave * 32;
  const u16* aSrc = A + (size_t)(m0 + rowA0 + srowB) * K + schunk * 8;
  const u16* bSrc = Bt + (size_t)(n0 + rowA0 + srowB) * K + schunk * 8;
  u16* aDst = &As[rowA0 * 64];
  u16* bDst = &Bs[rowA0 * 64];
  const size_t rstep = (size_t)8 * K;

  const int rx = lr & 7;

  for (int k0 = 0; k0 < K; k0 += 64) {
    __syncthreads();
#pragma unroll
    for (int c = 0; c < 4; ++c) {
      gld16(aSrc + c * rstep + k0, aDst + c * 8 * 64);
      gld16(bSrc + c * rstep + k0, bDst + c * 8 * 64);
    }
    __syncthreads();

#pragma unroll
    for (int h = 0; h < 2; ++h) {
      short8 aF[4], bF[4];
      const int rc = ((quad + 4 * h) ^ rx) * 8;
#pragma unroll
      for (int t = 0; t < 4; ++t) {
        aF[t] = *(const short8*)&As[(wm * 64 + t * 16 + lr) * 64 + rc];
        bF[t] = *(const short8*)&Bs[(wn * 64 + t * 16 + lr) * 64 + rc];
      }
#pragma unroll
      for (int mt = 0; mt < 4; ++mt)
#pragma unroll
        for (int nt = 0; nt < 4; ++nt)
          acc[mt][nt] = __builtin_amdgcn_mfma_f32_16x16x32_bf16(
              aF[mt], bF[nt], acc[mt][nt], 0, 0, 0);
    }
  }

#pragma unroll
  for (int mt = 0; mt < 4; ++mt)
#pragma unroll
    for (int nt = 0; nt < 4; ++nt)
#pragma unroll
      for (int r = 0; r < 4; ++r) {
        int row = m0 + wm * 64 + mt * 16 + quad * 4 + r;
        int col = n0 + wn * 64 + nt * 16 + lr;
        C[(size_t)row * N + col] = acc[mt][nt][r];
      }
}

// ---------- fallback: naive dequant-on-the-fly ----------
__global__ void naive(const float* __restrict__ x, const int* __restrict__ qw,
                      const int* __restrict__ qz, const int* __restrict__ qs,
                      const float* __restrict__ qsz, const float* __restrict__ qss,
                      const int* __restrict__ gidx, float* __restrict__ out,
                      int M, int N, int K) {
  int n = blockIdx.x * 64 + (threadIdx.x & 63);
  int m = blockIdx.y * 4 + (threadIdx.x >> 6);
  if (n >= N || m >= M) return;
  float acc = 0.f;
  for (int kk = 0; kk < K / 8; ++kk) {
    int w32 = qw[(size_t)kk * N + n];
#pragma unroll
    for (int s = 0; s < 8; ++s) {
      int k = kk * 8 + s;
      int g = gidx[k];
      int zq = ((qz[(size_t)g * (N >> 3) + (n >> 3)] >> (4 * (n & 7))) & 15) + 1;
      float sc = ((float)qs[(size_t)g * N + n] - qsz[g]) * qss[g];
      acc += x[(size_t)m * K + k] * ((float)((w32 >> (4 * s)) & 15) - (float)zq) * sc;
    }
  }
  out[(size_t)m * N + n] = acc;
}

extern "C" void kernel_launch(void* const* d_in, const int* in_sizes, int n_in,
                              void* d_out, int out_size, void* d_ws, size_t ws_size,
                              hipStream_t stream) {
  const float* x = (const float*)d_in[0];
  const int* qw = (const int*)d_in[1];
  const int* qz = (const int*)d_in[2];
  const int* qs = (const int*)d_in[3];
  const float* qsz = (const float*)d_in[4];
  const float* qss = (const float*)d_in[5];
  const int* gidx = (const int*)d_in[6];
  const int IN = in_sizes[6];                                   // 4096
  const int OUT = (int)(((long long)in_sizes[1] * 8) / IN);     // 4096
  const int M = in_sizes[0] / IN;                               // 8192
  float* out = (float*)d_out;

  size_t bytesW = (size_t)IN * OUT * 2;
  size_t bytesX = (size_t)M * IN * 2;
  bool haveWs = (ws_size >= bytesW + bytesX);
  bool fast256 = haveWs && (M % 256 == 0) && (OUT % 256 == 0) &&
                 (IN % 128 == 0) && (IN >= 256);
  bool fast128 = haveWs && (M % 128 == 0) && (OUT % 128 == 0) && (IN % 128 == 0);

  if (fast256 || fast128) {
    u16* Wt = (u16*)d_ws;
    u16* Xb = (u16*)((char*)d_ws + bytesW);
    long long n4 = (long long)M * IN / 4;
    int cb = (int)((n4 + 255) / 256);
    xconv<<<cb, 256, 0, stream>>>(x, Xb, n4);
    dequant<<<dim3(OUT / 64, IN / 128), 256, 0, stream>>>(qw, qz, qs, qsz, qss,
                                                          gidx, Wt, IN, OUT);
    if (fast256) {
      int nblk = (M / 256) * (OUT / 256);
      gemm256<<<dim3(nblk), 512, 0, stream>>>(Xb, Wt, out, M, OUT, IN);
    } else {
      gemm<<<dim3(OUT / 128, M / 128), 256, 0, stream>>>(Xb, Wt, out, M, OUT, IN);
    }
  } else {
    naive<<<dim3((OUT + 63) / 64, (M + 3) / 4), 256, 0, stream>>>(
        x, qw, qz, qs, qsz, qss, gidx, out, M, OUT, IN);
  }
}

// Round 4
// 512.048 us; speedup vs baseline: 1.0010x; 1.0010x over previous
//
#include <hip/hip_runtime.h>

typedef __attribute__((ext_vector_type(8))) short short8;
typedef __attribute__((ext_vector_type(4))) float floatx4;
typedef __attribute__((ext_vector_type(16))) float f32x16;
typedef unsigned int u32;
typedef unsigned short u16;

// ---------- helpers ----------
__device__ __forceinline__ u16 f2bf(float f) {
  u32 u = __float_as_uint(f);
  u += 0x7FFFu + ((u >> 16) & 1u);   // RNE
  return (u16)(u >> 16);
}

typedef const __attribute__((address_space(1))) u32* gp1_t;
typedef __attribute__((address_space(3))) u32* lp3_t;

__device__ __forceinline__ void gld16(const void* g, void* l) {
  // async global -> LDS, 16B per lane; LDS dest is wave-uniform base + lane*16
  __builtin_amdgcn_global_load_lds((gp1_t)g, (lp3_t)l, 16, 0, 0);
}

// ---------- kernel 1: x fp32 -> bf16 ----------
__global__ __launch_bounds__(256) void xconv(const float* __restrict__ x,
                                             u16* __restrict__ xb, long long n4) {
  long long i = (long long)blockIdx.x * 256 + threadIdx.x;
  if (i >= n4) return;
  float4 v = ((const float4*)x)[i];
  ushort4 o;
  o.x = f2bf(v.x); o.y = f2bf(v.y); o.z = f2bf(v.z); o.w = f2bf(v.w);
  ((ushort4*)xb)[i] = o;
}

// ---------- kernel 2: dequant int4 -> Wt[n][k] bf16 (write-coalesced) ----------
// Old version stored 16B per lane at 8KB stride (64 scattered lines per store
// instr).  New: per block a 64n x 128k tile; phase 1 reads qw coalesced
// (lanes along n) and dequants into a padded LDS tile; phase 2 writes Wt
// coalesced (lanes along k, 64B per thread).
__global__ __launch_bounds__(256) void dequant(
    const int* __restrict__ qw, const int* __restrict__ qz,
    const int* __restrict__ qs, const float* __restrict__ qsz,
    const float* __restrict__ qss, const int* __restrict__ gidx,
    u16* __restrict__ Wt, int IN, int OUT) {
  __shared__ u16 Lt[64][136];   // row stride 272B = 17 x 16B -> spread banks
  const int t = threadIdx.x;
  const int n0 = blockIdx.x * 64;
  const int k0 = blockIdx.y * 128;

  // phase 1: lanes along n (coalesced qw/qz/qs reads)
  {
    const int nl = t & 63, kw = t >> 6;        // kw 0..3
    const int n = n0 + nl;
#pragma unroll
    for (int j = 0; j < 4; ++j) {
      const int widx = kw + j * 4;             // packed word 0..15 (8 k each)
      const int g = gidx[k0 + widx * 8];       // wave-uniform
      const int zq = ((qz[(size_t)g * (OUT >> 3) + (n >> 3)] >> (4 * (n & 7))) & 15) + 1;
      const float sc = ((float)qs[(size_t)g * OUT + n] - qsz[g]) * qss[g];
      const int w32 = qw[(size_t)(k0 / 8 + widx) * OUT + n];
      u16 o[8];
#pragma unroll
      for (int s = 0; s < 8; ++s)
        o[s] = f2bf((float)(((w32 >> (4 * s)) & 15) - zq) * sc);
      uint4 pk;
      pk.x = (u32)o[0] | ((u32)o[1] << 16);
      pk.y = (u32)o[2] | ((u32)o[3] << 16);
      pk.z = (u32)o[4] | ((u32)o[5] << 16);
      pk.w = (u32)o[6] | ((u32)o[7] << 16);
      *(uint4*)&Lt[nl][widx * 8] = pk;
    }
  }
  __syncthreads();

  // phase 2: lanes along k (coalesced Wt writes, 64B/thread)
  {
    const int nl = t >> 2, kq = t & 3;         // 64 rows x 4 quads of 32 k
    u16* dst = Wt + (size_t)(n0 + nl) * IN + k0 + kq * 32;
#pragma unroll
    for (int i = 0; i < 4; ++i)
      *(uint4*)(dst + i * 8) = *(const uint4*)&Lt[nl][kq * 32 + i * 8];
  }
}

// ---------- kernel 3: 256x256 4-phase 32x32-MFMA bf16 GEMM ----------
// Same schedule as round 3 (verified cadence), but LDS layout switched to
// 64B rows: each BK=64 tile is 2 sub-tiles of 32 k ([buf][sub][256*32]).
// This reproduces the round-1 layout whose read pattern MEASURED 0 bank
// conflicts (round 3's 128B rows measured 2.5e7 conflict cycles).
// Swizzle: 4 granules (16B) per 64B row; store logical granule g at physical
// g ^ ((row>>1)&3) (applied on the global source col; gld_lds writes
// linearly), undone on ds_read.  Per-8-lane read group spans 8 distinct
// bank-starts ((row&1)*16 + g*4) -> conflict-free per round-1 measurement.
// Cadence (iter i computes tiles 2i/buf0, 2i+1/buf1; 4 gld16 per phase):
//   ph0(buf0,q0,+B): stage A(1,t+1)   ph1(buf0,q1): stage B(0,t+2), VM4
//   ph2(buf1,q0,+B): stage A(0,t+2)   ph3(buf1,q1): stage B(1,t+3), VM4
// vmcnt(4) at ph1-end drains buf1 (B from prev ph3 + A from ph0) before ph2;
// at ph3-end drains buf0 before next ph0.  Never 0 in steady state.
#define VM4 asm volatile("s_waitcnt vmcnt(4)" ::: "memory")
#define VM0 asm volatile("s_waitcnt vmcnt(0)" ::: "memory")

__global__ __launch_bounds__(512, 2) void gemm256(const u16* __restrict__ A,
                                                  const u16* __restrict__ Bt,
                                                  float* __restrict__ C,
                                                  int M, int N, int K) {
  __shared__ u16 As[2][2][8192];   // [buf][sub][256 rows * 32 elems]
  __shared__ u16 Bs[2][2][8192];
  const int tid = threadIdx.x;
  const int lane = tid & 63;
  const int wave = tid >> 6;          // 0..7
  const int wm = wave >> 2;           // 0..1
  const int wn = wave & 3;            // 0..3
  const int l31 = lane & 31, hi = lane >> 5;

  // bijective XCD-aware block swizzle (m204 form)
  const int nbx = N >> 8;
  const int nwg = gridDim.x;
  const int bid = blockIdx.x;
  const int q8 = nwg >> 3, r8 = nwg & 7;
  const int xcd = bid & 7, loc = bid >> 3;
  const int swz = (xcd < r8 ? xcd * (q8 + 1) : r8 * (q8 + 1) + (xcd - r8) * q8) + loc;
  const int n0 = (swz % nbx) << 8;
  const int m0 = (swz / nbx) << 8;

  f32x16 acc[4][2] = {};

  // ---- staging source (per-thread; carries the store swizzle) ----
  // one gld16 = 1024B = 16 rows x 64B; lane -> row += lane>>2, granule lane&3;
  // source granule = (lane&3) ^ ((row>>1)&3) = (lane&3) ^ ((lane>>3)&3)
  const int srow = lane >> 2;
  const int sg = ((lane & 3) ^ ((lane >> 3) & 3)) * 8;
  const u16* aS = A + (size_t)(m0 + wave * 16 + srow) * K + sg;
  const u16* bS = Bt + (size_t)(n0 + wave * 16 + srow) * K + sg;

#define STAGE_A(buf, kt) do {                                                 \
    _Pragma("unroll") for (int h_ = 0; h_ < 2; ++h_)                          \
      _Pragma("unroll") for (int sb_ = 0; sb_ < 2; ++sb_)                     \
        gld16(aS + (size_t)h_ * 128 * K + (size_t)(kt) * 64 + sb_ * 32,       \
              &As[buf][sb_][(h_ * 128 + wave * 16) * 32]);                    \
  } while (0)
#define STAGE_B(buf, kt) do {                                                 \
    _Pragma("unroll") for (int h_ = 0; h_ < 2; ++h_)                          \
      _Pragma("unroll") for (int sb_ = 0; sb_ < 2; ++sb_)                     \
        gld16(bS + (size_t)h_ * 128 * K + (size_t)(kt) * 64 + sb_ * 32,       \
              &Bs[buf][sb_][(h_ * 128 + wave * 16) * 32]);                    \
  } while (0)

  // ---- fragment read bases (swizzle undone on granule) ----
  // MFMA k-step ks (16 k): sub = ks>>1, logical granule = (ks&1)*2 + hi
  const int rsw = (l31 >> 1) & 3;
  int ko[4];
#pragma unroll
  for (int ks = 0; ks < 4; ++ks) ko[ks] = ((((ks & 1) * 2 + hi)) ^ rsw) * 8;
  const u32 aBase = (u32)(wm * 128 + l31) * 32;
  const u32 bBase = (u32)(wn * 64 + l31) * 32;
  const u16* a0p[2] = { &As[0][0][aBase], &As[0][1][aBase] };
  const u16* a1p[2] = { &As[1][0][aBase], &As[1][1][aBase] };
  const u16* b0p[2] = { &Bs[0][0][bBase], &Bs[0][1][bBase] };
  const u16* b1p[2] = { &Bs[1][0][bBase], &Bs[1][1][bBase] };

  short8 aF[2][4], bF[2][4];

#define PHASE(AP, BP, q, LOADB, STG, VMW) do {                                \
    if (LOADB) {                                                              \
      _Pragma("unroll") for (int nt = 0; nt < 2; ++nt)                        \
        _Pragma("unroll") for (int ks = 0; ks < 4; ++ks)                      \
          bF[nt][ks] = *(const short8*)(BP[ks >> 1] + nt * 1024 + ko[ks]);    \
    }                                                                         \
    _Pragma("unroll") for (int j = 0; j < 2; ++j)                             \
      _Pragma("unroll") for (int ks = 0; ks < 4; ++ks)                        \
        aF[j][ks] =                                                           \
            *(const short8*)(AP[ks >> 1] + (2 * (q) + j) * 1024 + ko[ks]);    \
    STG;                                                                      \
    __builtin_amdgcn_s_barrier();                                             \
    __builtin_amdgcn_s_setprio(1);                                            \
    _Pragma("unroll") for (int ks = 0; ks < 4; ++ks)                          \
      _Pragma("unroll") for (int j = 0; j < 2; ++j)                           \
        _Pragma("unroll") for (int nt = 0; nt < 2; ++nt)                      \
          acc[2 * (q) + j][nt] = __builtin_amdgcn_mfma_f32_32x32x16_bf16(     \
              aF[j][ks], bF[nt][ks], acc[2 * (q) + j][nt], 0, 0, 0);          \
    __builtin_amdgcn_s_setprio(0);                                            \
    VMW;                                                                      \
    __builtin_amdgcn_s_barrier();                                             \
  } while (0)

  // ---- prologue: buf0 <- tile0 (B,A), buf1.B <- tile1; wait buf0 only ----
  STAGE_B(0, 0);
  STAGE_A(0, 0);
  STAGE_B(1, 1);
  VM4;                                    // oldest 8 = buf0 complete
  __builtin_amdgcn_s_barrier();

  const int NI = K >> 7;                  // iters of 2 K-tiles
  for (int i = 0; i < NI; ++i) {
    const int kt = 2 * i;
    const bool full = (i < NI - 1);
    PHASE(a0p, b0p, 0, 1, { STAGE_A(1, kt + 1); }, (void)0);
    PHASE(a0p, b0p, 1, 0, { if (full) STAGE_B(0, kt + 2); },
          { if (full) { VM4; } else { VM0; } });
    PHASE(a1p, b1p, 0, 1, { if (full) STAGE_A(0, kt + 2); }, (void)0);
    PHASE(a1p, b1p, 1, 0, { if (full) STAGE_B(1, kt + 3); },
          { if (full) { VM4; } });
  }
#undef PHASE
#undef STAGE_A
#undef STAGE_B

  // ---- epilogue: C/D col=lane&31, row=(r&3)+8*(r>>2)+4*hi ----
#pragma unroll
  for (int mt = 0; mt < 4; ++mt)
#pragma unroll
    for (int nt = 0; nt < 2; ++nt)
#pragma unroll
      for (int r = 0; r < 16; ++r) {
        int row = m0 + wm * 128 + mt * 32 + (r & 3) + 8 * (r >> 2) + 4 * hi;
        int col = n0 + wn * 64 + nt * 32 + l31;
        C[(size_t)row * N + col] = acc[mt][nt][r];
      }
}

// ---------- kernel 3b (fallback): 128x128 bf16 GEMM ----------
__global__ __launch_bounds__(256) void gemm(const u16* __restrict__ A,
                                            const u16* __restrict__ Bt,
                                            float* __restrict__ C,
                                            int M, int N, int K) {
  __shared__ u16 As[128 * 64];
  __shared__ u16 Bs[128 * 64];
  const int tid = threadIdx.x;
  const int lane = tid & 63;
  const int wave = tid >> 6;
  const int wm = wave & 1, wn = wave >> 1;
  const int lr = lane & 15, quad = lane >> 4;
  const int m0 = blockIdx.y * 128, n0 = blockIdx.x * 128;

  floatx4 acc[4][4] = {};

  const int srowB = (lane >> 3);
  const int schunk = (lane & 7) ^ srowB;
  const int rowA0 = wave * 32;
  const u16* aSrc = A + (size_t)(m0 + rowA0 + srowB) * K + schunk * 8;
  const u16* bSrc = Bt + (size_t)(n0 + rowA0 + srowB) * K + schunk * 8;
  u16* aDst = &As[rowA0 * 64];
  u16* bDst = &Bs[rowA0 * 64];
  const size_t rstep = (size_t)8 * K;

  const int rx = lr & 7;

  for (int k0 = 0; k0 < K; k0 += 64) {
    __syncthreads();
#pragma unroll
    for (int c = 0; c < 4; ++c) {
      gld16(aSrc + c * rstep + k0, aDst + c * 8 * 64);
      gld16(bSrc + c * rstep + k0, bDst + c * 8 * 64);
    }
    __syncthreads();

#pragma unroll
    for (int h = 0; h < 2; ++h) {
      short8 aF[4], bF[4];
      const int rc = ((quad + 4 * h) ^ rx) * 8;
#pragma unroll
      for (int t = 0; t < 4; ++t) {
        aF[t] = *(const short8*)&As[(wm * 64 + t * 16 + lr) * 64 + rc];
        bF[t] = *(const short8*)&Bs[(wn * 64 + t * 16 + lr) * 64 + rc];
      }
#pragma unroll
      for (int mt = 0; mt < 4; ++mt)
#pragma unroll
        for (int nt = 0; nt < 4; ++nt)
          acc[mt][nt] = __builtin_amdgcn_mfma_f32_16x16x32_bf16(
              aF[mt], bF[nt], acc[mt][nt], 0, 0, 0);
    }
  }

#pragma unroll
  for (int mt = 0; mt < 4; ++mt)
#pragma unroll
    for (int nt = 0; nt < 4; ++nt)
#pragma unroll
      for (int r = 0; r < 4; ++r) {
        int row = m0 + wm * 64 + mt * 16 + quad * 4 + r;
        int col = n0 + wn * 64 + nt * 16 + lr;
        C[(size_t)row * N + col] = acc[mt][nt][r];
      }
}

// ---------- fallback: naive dequant-on-the-fly ----------
__global__ void naive(const float* __restrict__ x, const int* __restrict__ qw,
                      const int* __restrict__ qz, const int* __restrict__ qs,
                      const float* __restrict__ qsz, const float* __restrict__ qss,
                      const int* __restrict__ gidx, float* __restrict__ out,
                      int M, int N, int K) {
  int n = blockIdx.x * 64 + (threadIdx.x & 63);
  int m = blockIdx.y * 4 + (threadIdx.x >> 6);
  if (n >= N || m >= M) return;
  float acc = 0.f;
  for (int kk = 0; kk < K / 8; ++kk) {
    int w32 = qw[(size_t)kk * N + n];
#pragma unroll
    for (int s = 0; s < 8; ++s) {
      int k = kk * 8 + s;
      int g = gidx[k];
      int zq = ((qz[(size_t)g * (N >> 3) + (n >> 3)] >> (4 * (n & 7))) & 15) + 1;
      float sc = ((float)qs[(size_t)g * N + n] - qsz[g]) * qss[g];
      acc += x[(size_t)m * K + k] * ((float)((w32 >> (4 * s)) & 15) - (float)zq) * sc;
    }
  }
  out[(size_t)m * N + n] = acc;
}

extern "C" void kernel_launch(void* const* d_in, const int* in_sizes, int n_in,
                              void* d_out, int out_size, void* d_ws, size_t ws_size,
                              hipStream_t stream) {
  const float* x = (const float*)d_in[0];
  const int* qw = (const int*)d_in[1];
  const int* qz = (const int*)d_in[2];
  const int* qs = (const int*)d_in[3];
  const float* qsz = (const float*)d_in[4];
  const float* qss = (const float*)d_in[5];
  const int* gidx = (const int*)d_in[6];
  const int IN = in_sizes[6];                                   // 4096
  const int OUT = (int)(((long long)in_sizes[1] * 8) / IN);     // 4096
  const int M = in_sizes[0] / IN;                               // 8192
  float* out = (float*)d_out;

  size_t bytesW = (size_t)IN * OUT * 2;
  size_t bytesX = (size_t)M * IN * 2;
  bool haveWs = (ws_size >= bytesW + bytesX);
  bool fast256 = haveWs && (M % 256 == 0) && (OUT % 256 == 0) &&
                 (IN % 128 == 0) && (IN >= 256);
  bool fast128 = haveWs && (M % 128 == 0) && (OUT % 128 == 0) && (IN % 128 == 0);

  if (fast256 || fast128) {
    u16* Wt = (u16*)d_ws;
    u16* Xb = (u16*)((char*)d_ws + bytesW);
    long long n4 = (long long)M * IN / 4;
    int cb = (int)((n4 + 255) / 256);
    xconv<<<cb, 256, 0, stream>>>(x, Xb, n4);
    dequant<<<dim3(OUT / 64, IN / 128), 256, 0, stream>>>(qw, qz, qs, qsz, qss,
                                                          gidx, Wt, IN, OUT);
    if (fast256) {
      int nblk = (M / 256) * (OUT / 256);
      gemm256<<<dim3(nblk), 512, 0, stream>>>(Xb, Wt, out, M, OUT, IN);
    } else {
      gemm<<<dim3(OUT / 128, M / 128), 256, 0, stream>>>(Xb, Wt, out, M, OUT, IN);
    }
  } else {
    naive<<<dim3((OUT + 63) / 64, (M + 3) / 4), 256, 0, stream>>>(
        x, qw, qz, qs, qsz, qss, gidx, out, M, OUT, IN);
  }
}

// Round 5
// 475.161 us; speedup vs baseline: 1.0787x; 1.0776x over previous
//
#include <hip/hip_runtime.h>

typedef __attribute__((ext_vector_type(8))) short short8;
typedef __attribute__((ext_vector_type(4))) float floatx4;
typedef unsigned int u32;
typedef unsigned short u16;

// ---------- helpers ----------
__device__ __forceinline__ u16 f2bf(float f) {
  u32 u = __float_as_uint(f);
  u += 0x7FFFu + ((u >> 16) & 1u);   // RNE
  return (u16)(u >> 16);
}

typedef const __attribute__((address_space(1))) u32* gp1_t;
typedef __attribute__((address_space(3))) u32* lp3_t;

__device__ __forceinline__ void gld16(const void* g, void* l) {
  // async global -> LDS, 16B per lane; LDS dest is wave-uniform base + lane*16
  __builtin_amdgcn_global_load_lds((gp1_t)g, (lp3_t)l, 16, 0, 0);
}

// ---------- kernel 1: x fp32 -> bf16 (grid-stride) ----------
__global__ __launch_bounds__(256) void xconv(const float* __restrict__ x,
                                             u16* __restrict__ xb, long long n4) {
  const long long stride = (long long)gridDim.x * 256;
  for (long long i = (long long)blockIdx.x * 256 + threadIdx.x; i < n4; i += stride) {
    float4 v = ((const float4*)x)[i];
    ushort4 o;
    o.x = f2bf(v.x); o.y = f2bf(v.y); o.z = f2bf(v.z); o.w = f2bf(v.w);
    ((ushort4*)xb)[i] = o;
  }
}

// ---------- kernel 2: dequant int4 -> Wt[n][k] bf16 (write-coalesced) ----------
__global__ __launch_bounds__(256) void dequant(
    const int* __restrict__ qw, const int* __restrict__ qz,
    const int* __restrict__ qs, const float* __restrict__ qsz,
    const float* __restrict__ qss, const int* __restrict__ gidx,
    u16* __restrict__ Wt, int IN, int OUT) {
  __shared__ u16 Lt[64][136];   // row stride 272B -> spread banks
  const int t = threadIdx.x;
  const int n0 = blockIdx.x * 64;
  const int k0 = blockIdx.y * 128;

  // phase 1: lanes along n (coalesced qw/qz/qs reads)
  {
    const int nl = t & 63, kw = t >> 6;        // kw 0..3
    const int n = n0 + nl;
#pragma unroll
    for (int j = 0; j < 4; ++j) {
      const int widx = kw + j * 4;             // packed word 0..15 (8 k each)
      const int g = gidx[k0 + widx * 8];       // wave-uniform
      const int zq = ((qz[(size_t)g * (OUT >> 3) + (n >> 3)] >> (4 * (n & 7))) & 15) + 1;
      const float sc = ((float)qs[(size_t)g * OUT + n] - qsz[g]) * qss[g];
      const int w32 = qw[(size_t)(k0 / 8 + widx) * OUT + n];
      u16 o[8];
#pragma unroll
      for (int s = 0; s < 8; ++s)
        o[s] = f2bf((float)(((w32 >> (4 * s)) & 15) - zq) * sc);
      uint4 pk;
      pk.x = (u32)o[0] | ((u32)o[1] << 16);
      pk.y = (u32)o[2] | ((u32)o[3] << 16);
      pk.z = (u32)o[4] | ((u32)o[5] << 16);
      pk.w = (u32)o[6] | ((u32)o[7] << 16);
      *(uint4*)&Lt[nl][widx * 8] = pk;
    }
  }
  __syncthreads();

  // phase 2: lanes along k (coalesced Wt writes, 64B/thread)
  {
    const int nl = t >> 2, kq = t & 3;         // 64 rows x 4 quads of 32 k
    u16* dst = Wt + (size_t)(n0 + nl) * IN + k0 + kq * 32;
#pragma unroll
    for (int i = 0; i < 4; ++i)
      *(uint4*)(dst + i * 8) = *(const uint4*)&Lt[nl][kq * 32 + i * 8];
  }
}

// ---------- kernel 3: 256x256 bf16 GEMM, 2 barriers per K-tile ----------
// C = A(MxK)*Bt(NxK)^T.  8 waves (2m x 4n), per-wave 128x64 C, 16x16x32
// MFMA, BK=64, buf0 = even K-tiles, buf1 = odd.  Round-2 geometry (proven
// fastest + its read pattern), but the 8-phase lockstep (2 barriers/phase ->
// reads and MFMA strictly alternate, measured additive ~1330cyc/phase) is
// collapsed to 2 barriers per TILE:
//   vmcnt(4); entry barrier;
//   issue bF(8) + aL(8) ds_read_b128; issue stage A(b^1)<-t+1 (4 gld16);
//   MFMA q0 (16, setprio);
//   issue aH(8) ds_read; MFMA q1 (16);
//   mid barrier;                       // orders all waves' bF reads first
//   issue stage B(b)<-t+2 (4 gld16);
//   MFMA q2 (16); MFMA q3 (16);
// Compiler inserts fine-grained lgkmcnt between ds_read and MFMA (m97
// behavior), so each wave's LDS stream overlaps the MFMA clusters; waves
// also drift between the two barriers (role-split -> setprio pays).
// Race-freedom: A(b^1) last read pre-entry-barrier (prev tile); B(b) read
// only at tile entry, ordered by mid barrier; vmcnt(4) at entry = all but
// the newest stage (B<-t+2, 4 loads) landed => A(t),B(t) complete.
// Swizzle (round 2): row stride 64 bf16 = 128B = 8 granules; store granule
// c at c^(row&7) (pre-swizzled global source; gld_lds writes linearly),
// undone on ds_read.
#define VM4 asm volatile("s_waitcnt vmcnt(4)" ::: "memory")
#define VM0 asm volatile("s_waitcnt vmcnt(0)" ::: "memory")

__global__ __launch_bounds__(512, 2) void gemm256(const u16* __restrict__ A,
                                                  const u16* __restrict__ Bt,
                                                  float* __restrict__ C,
                                                  int M, int N, int K) {
  __shared__ u16 As[2][16384];
  __shared__ u16 Bs[2][16384];
  const int tid = threadIdx.x;
  const int lane = tid & 63;
  const int wave = tid >> 6;          // 0..7
  const int wm = wave >> 2;           // 0..1
  const int wn = wave & 3;            // 0..3
  const int lr = lane & 15, quad = lane >> 4;

  // bijective XCD-aware block swizzle (m204 form)
  const int nbx = N >> 8;
  const int nwg = gridDim.x;
  const int bid = blockIdx.x;
  const int q8 = nwg >> 3, r8 = nwg & 7;
  const int xcd = bid & 7, loc = bid >> 3;
  const int swz = (xcd < r8 ? xcd * (q8 + 1) : r8 * (q8 + 1) + (xcd - r8) * q8) + loc;
  const int n0 = (swz % nbx) << 8;
  const int m0 = (swz / nbx) << 8;

  floatx4 acc[8][4] = {};

  // ---- staging source (per-thread; carries the store swizzle) ----
  // one gld16 covers 64 rows x 64 k: wave w rows w*8+(lane>>3), granule
  // lane&7, source granule ^= row&7
  const int srow = lane >> 3;
  const int sch8 = ((lane & 7) ^ (srow & 7)) * 8;
  const u16* aS = A + (size_t)(m0 + wave * 8 + srow) * K + sch8;
  const u16* bS = Bt + (size_t)(n0 + wave * 8 + srow) * K + sch8;

#define STAGE_A(buf, kt) do {                                                 \
    _Pragma("unroll") for (int h_ = 0; h_ < 2; ++h_) {                        \
      const u16* s_ = aS + (size_t)h_ * 128 * K + (size_t)(kt) * 64;          \
      u16* d_ = &As[buf][(h_ * 128 + wave * 8) * 64];                         \
      gld16(s_, d_); gld16(s_ + (size_t)64 * K, d_ + 4096);                   \
    } } while (0)
#define STAGE_B(buf, kt) do {                                                 \
    _Pragma("unroll") for (int h_ = 0; h_ < 2; ++h_) {                        \
      const u16* s_ = bS + (size_t)h_ * 128 * K + (size_t)(kt) * 64;          \
      u16* d_ = &Bs[buf][(h_ * 128 + wave * 8) * 64];                         \
      gld16(s_, d_); gld16(s_ + (size_t)64 * K, d_ + 4096);                   \
    } } while (0)

  // ---- fragment read bases (swizzle undone; row&7 == lr&7) ----
  const int rl = lr & 7;
  const int cs0 = ((0 * 4 + quad) ^ rl) * 8;   // ksub 0
  const int cs1 = ((1 * 4 + quad) ^ rl) * 8;   // ksub 1
  const u16* a0rd = &As[0][(wm * 128 + lr) * 64];
  const u16* a1rd = &As[1][(wm * 128 + lr) * 64];
  const u16* b0rd = &Bs[0][(wn * 64 + lr) * 64];
  const u16* b1rd = &Bs[1][(wn * 64 + lr) * 64];

#define MFMA16(JB, AARR)                                                      \
    __builtin_amdgcn_s_setprio(1);                                            \
    _Pragma("unroll") for (int s = 0; s < 2; ++s)                             \
      _Pragma("unroll") for (int j = 0; j < 2; ++j)                           \
        _Pragma("unroll") for (int nt = 0; nt < 4; ++nt)                      \
          acc[(JB) + j][nt] = __builtin_amdgcn_mfma_f32_16x16x32_bf16(        \
              AARR[((JB) & 2) + j][s], bF[nt][s], acc[(JB) + j][nt], 0, 0, 0);\
    __builtin_amdgcn_s_setprio(0);

#define TILE(ARD, BRD, STGA, STGB, VMW) do {                                  \
    VMW;                                                                      \
    __builtin_amdgcn_s_barrier();                                             \
    short8 bF[4][2], aL[4][2], aH[4][2];                                      \
    _Pragma("unroll") for (int nt = 0; nt < 4; ++nt) {                        \
      bF[nt][0] = *(const short8*)((BRD) + nt * 1024 + cs0);                  \
      bF[nt][1] = *(const short8*)((BRD) + nt * 1024 + cs1);                  \
    }                                                                         \
    _Pragma("unroll") for (int j = 0; j < 4; ++j) {                           \
      aL[j][0] = *(const short8*)((ARD) + j * 1024 + cs0);                    \
      aL[j][1] = *(const short8*)((ARD) + j * 1024 + cs1);                    \
    }                                                                         \
    STGA;                                                                     \
    MFMA16(0, aL)                                                             \
    _Pragma("unroll") for (int j = 0; j < 4; ++j) {                           \
      aH[j][0] = *(const short8*)((ARD) + (4 + j) * 1024 + cs0);              \
      aH[j][1] = *(const short8*)((ARD) + (4 + j) * 1024 + cs1);              \
    }                                                                         \
    MFMA16(2, aL)                                                             \
    __builtin_amdgcn_s_barrier();   /* mid: B-reads before B-overwrite */     \
    STGB;                                                                     \
    MFMA16(4, aH)                                                             \
    MFMA16(6, aH)                                                             \
  } while (0)

  // ---- prologue: B0, A0 (buf0, tile0), B1 (buf1, tile1) ----
  STAGE_B(0, 0);
  STAGE_A(0, 0);
  STAGE_B(1, 1);

  const int NI = K >> 7;                  // iters of 2 K-tiles
  for (int i = 0; i < NI - 1; ++i) {
    const int kt = 2 * i;
    TILE(a0rd, b0rd, { STAGE_A(1, kt + 1); }, { STAGE_B(0, kt + 2); }, VM4);
    TILE(a1rd, b1rd, { STAGE_A(0, kt + 2); }, { STAGE_B(1, kt + 3); }, VM4);
  }
  // last pair: tiles 2*NI-2 (buf0), 2*NI-1 (buf1)
  TILE(a0rd, b0rd, { STAGE_A(1, 2 * NI - 1); }, (void)0, VM4);
  TILE(a1rd, b1rd, (void)0, (void)0, VM0);
#undef TILE
#undef MFMA16
#undef STAGE_A
#undef STAGE_B

  // ---- epilogue: C/D layout col=lane&15, row=quad*4+reg ----
#pragma unroll
  for (int mt = 0; mt < 8; ++mt)
#pragma unroll
    for (int nt = 0; nt < 4; ++nt)
#pragma unroll
      for (int r = 0; r < 4; ++r) {
        int row = m0 + wm * 128 + mt * 16 + quad * 4 + r;
        int col = n0 + wn * 64 + nt * 16 + lr;
        C[(size_t)row * N + col] = acc[mt][nt][r];
      }
}

// ---------- kernel 3b (fallback): 128x128 bf16 GEMM ----------
__global__ __launch_bounds__(256) void gemm(const u16* __restrict__ A,
                                            const u16* __restrict__ Bt,
                                            float* __restrict__ C,
                                            int M, int N, int K) {
  __shared__ u16 As[128 * 64];
  __shared__ u16 Bs[128 * 64];
  const int tid = threadIdx.x;
  const int lane = tid & 63;
  const int wave = tid >> 6;
  const int wm = wave & 1, wn = wave >> 1;
  const int lr = lane & 15, quad = lane >> 4;
  const int m0 = blockIdx.y * 128, n0 = blockIdx.x * 128;

  floatx4 acc[4][4] = {};

  const int srowB = (lane >> 3);
  const int schunk = (lane & 7) ^ srowB;
  const int rowA0 = wave * 32;
  const u16* aSrc = A + (size_t)(m0 + rowA0 + srowB) * K + schunk * 8;
  const u16* bSrc = Bt + (size_t)(n0 + rowA0 + srowB) * K + schunk * 8;
  u16* aDst = &As[rowA0 * 64];
  u16* bDst = &Bs[rowA0 * 64];
  const size_t rstep = (size_t)8 * K;

  const int rx = lr & 7;

  for (int k0 = 0; k0 < K; k0 += 64) {
    __syncthreads();
#pragma unroll
    for (int c = 0; c < 4; ++c) {
      gld16(aSrc + c * rstep + k0, aDst + c * 8 * 64);
      gld16(bSrc + c * rstep + k0, bDst + c * 8 * 64);
    }
    __syncthreads();

#pragma unroll
    for (int h = 0; h < 2; ++h) {
      short8 aF[4], bF[4];
      const int rc = ((quad + 4 * h) ^ rx) * 8;
#pragma unroll
      for (int t = 0; t < 4; ++t) {
        aF[t] = *(const short8*)&As[(wm * 64 + t * 16 + lr) * 64 + rc];
        bF[t] = *(const short8*)&Bs[(wn * 64 + t * 16 + lr) * 64 + rc];
      }
#pragma unroll
      for (int mt = 0; mt < 4; ++mt)
#pragma unroll
        for (int nt = 0; nt < 4; ++nt)
          acc[mt][nt] = __builtin_amdgcn_mfma_f32_16x16x32_bf16(
              aF[mt], bF[nt], acc[mt][nt], 0, 0, 0);
    }
  }

#pragma unroll
  for (int mt = 0; mt < 4; ++mt)
#pragma unroll
    for (int nt = 0; nt < 4; ++nt)
#pragma unroll
      for (int r = 0; r < 4; ++r) {
        int row = m0 + wm * 64 + mt * 16 + quad * 4 + r;
        int col = n0 + wn * 64 + nt * 16 + lr;
        C[(size_t)row * N + col] = acc[mt][nt][r];
      }
}

// ---------- fallback: naive dequant-on-the-fly ----------
__global__ void naive(const float* __restrict__ x, const int* __restrict__ qw,
                      const int* __restrict__ qz, const int* __restrict__ qs,
                      const float* __restrict__ qsz, const float* __restrict__ qss,
                      const int* __restrict__ gidx, float* __restrict__ out,
                      int M, int N, int K) {
  int n = blockIdx.x * 64 + (threadIdx.x & 63);
  int m = blockIdx.y * 4 + (threadIdx.x >> 6);
  if (n >= N || m >= M) return;
  float acc = 0.f;
  for (int kk = 0; kk < K / 8; ++kk) {
    int w32 = qw[(size_t)kk * N + n];
#pragma unroll
    for (int s = 0; s < 8; ++s) {
      int k = kk * 8 + s;
      int g = gidx[k];
      int zq = ((qz[(size_t)g * (N >> 3) + (n >> 3)] >> (4 * (n & 7))) & 15) + 1;
      float sc = ((float)qs[(size_t)g * N + n] - qsz[g]) * qss[g];
      acc += x[(size_t)m * K + k] * ((float)((w32 >> (4 * s)) & 15) - (float)zq) * sc;
    }
  }
  out[(size_t)m * N + n] = acc;
}

extern "C" void kernel_launch(void* const* d_in, const int* in_sizes, int n_in,
                              void* d_out, int out_size, void* d_ws, size_t ws_size,
                              hipStream_t stream) {
  const float* x = (const float*)d_in[0];
  const int* qw = (const int*)d_in[1];
  const int* qz = (const int*)d_in[2];
  const int* qs = (const int*)d_in[3];
  const float* qsz = (const float*)d_in[4];
  const float* qss = (const float*)d_in[5];
  const int* gidx = (const int*)d_in[6];
  const int IN = in_sizes[6];                                   // 4096
  const int OUT = (int)(((long long)in_sizes[1] * 8) / IN);     // 4096
  const int M = in_sizes[0] / IN;                               // 8192
  float* out = (float*)d_out;

  size_t bytesW = (size_t)IN * OUT * 2;
  size_t bytesX = (size_t)M * IN * 2;
  bool haveWs = (ws_size >= bytesW + bytesX);
  bool fast256 = haveWs && (M % 256 == 0) && (OUT % 256 == 0) &&
                 (IN % 256 == 0) && (IN >= 256);
  bool fast128 = haveWs && (M % 128 == 0) && (OUT % 128 == 0) && (IN % 128 == 0);

  if (fast256 || fast128) {
    u16* Wt = (u16*)d_ws;
    u16* Xb = (u16*)((char*)d_ws + bytesW);
    long long n4 = (long long)M * IN / 4;
    int cb = (int)((n4 + 255) / 256);
    if (cb > 2048) cb = 2048;
    xconv<<<cb, 256, 0, stream>>>(x, Xb, n4);
    dequant<<<dim3(OUT / 64, IN / 128), 256, 0, stream>>>(qw, qz, qs, qsz, qss,
                                                          gidx, Wt, IN, OUT);
    if (fast256) {
      int nblk = (M / 256) * (OUT / 256);
      gemm256<<<dim3(nblk), 512, 0, stream>>>(Xb, Wt, out, M, OUT, IN);
    } else {
      gemm<<<dim3(OUT / 128, M / 128), 256, 0, stream>>>(Xb, Wt, out, M, OUT, IN);
    }
  } else {
    naive<<<dim3((OUT + 63) / 64, (M + 3) / 4), 256, 0, stream>>>(
        x, qw, qz, qs, qsz, qss, gidx, out, M, OUT, IN);
  }
}